// Round 12
// baseline (703.975 us; speedup 1.0000x reference)
//
#include <hip/hip_runtime.h>
#include <cstdio>
#include <cstdint>

typedef _Float16 f16;
typedef _Float16 f16x4 __attribute__((ext_vector_type(4)));
typedef _Float16 f16x8 __attribute__((ext_vector_type(8)));
typedef float f32x4 __attribute__((ext_vector_type(4)));

#define GLL16(gp, lp)                                                          \
  __builtin_amdgcn_global_load_lds(                                            \
      (const __attribute__((address_space(1))) void*)(gp),                     \
      (__attribute__((address_space(3))) void*)(lp), 16, 0, 0)

#define BARX __builtin_amdgcn_s_barrier()
#define WAITV4 { asm volatile("s_waitcnt vmcnt(4)" ::: "memory"); __builtin_amdgcn_sched_barrier(0); }
#define WAITV0 { asm volatile("s_waitcnt vmcnt(0)" ::: "memory"); __builtin_amdgcn_sched_barrier(0); }
#define WAITL0 { asm volatile("s_waitcnt lgkmcnt(0)" ::: "memory"); __builtin_amdgcn_sched_barrier(0); }

// ---------------- fp32 -> fp16 elementwise (h) ----------------
__global__ void cvt_f32_f16_kernel(const float* __restrict__ in,
                                   f16* __restrict__ out, int n4) {
  int i = blockIdx.x * blockDim.x + threadIdx.x;
  if (i < n4) {
    f32x4 v = reinterpret_cast<const f32x4*>(in)[i];
    f16x4 o;
    o[0] = (f16)v[0]; o[1] = (f16)v[1]; o[2] = (f16)v[2]; o[3] = (f16)v[3];
    reinterpret_cast<f16x4*>(out)[i] = o;
  }
}

// ------- fp32 [R][C] -> fp16 transposed, 64x64 tiles, coalesced stores ------
__global__ void tr_cvt2_kernel(const float* __restrict__ inA,
                               const float* __restrict__ inB,
                               f16* __restrict__ out, size_t slotOff,
                               int C, size_t OS, int nA) {
  int slot = blockIdx.z;
  const float* src = (slot < nA) ? inA + (size_t)slot * 64 * gridDim.y * C : inB;
  f16* dst = out + (size_t)slot * slotOff;
  __shared__ f16 tl[4096];
  int t = threadIdx.x;
  int r0 = blockIdx.y * 64, c0 = blockIdx.x * 64;
  int br = (t >> 4) * 4, bc = (t & 15) * 4;
  f32x4 v[4];
#pragma unroll
  for (int i = 0; i < 4; ++i)
    v[i] = *(const f32x4*)&src[(size_t)(r0 + br + i) * C + c0 + bc];
#pragma unroll
  for (int cc = 0; cc < 4; ++cc) {
    int c = bc + cc;
    f16x4 o;
    o[0] = (f16)v[0][cc]; o[1] = (f16)v[1][cc];
    o[2] = (f16)v[2][cc]; o[3] = (f16)v[3][cc];
    *(f16x4*)&tl[c * 64 + (br ^ ((c & 7) * 8))] = o;
  }
  __syncthreads();
  int rw = (t & 7) * 8, cw = t >> 3;
#pragma unroll
  for (int j = 0; j < 2; ++j) {
    int c = cw + j * 32;
    f16x8 o = *(const f16x8*)&tl[c * 64 + (rw ^ ((c & 7) * 8))];
    *(f16x8*)&dst[(size_t)(c0 + c) * OS + r0 + rw] = o;
  }
}

// ===== persistent fused UG, mega-D geometry =================================
// Grid 256 = 1 block/CU. xcd=bid&7, idx=bid>>3, mt=idx&7, q=xcd*4+(idx>>3):
// XCD owns ntg in [xcd*36, xcd*36+36), all 8 mt (L2 locality, R8/R11-proven).
// Per block: 9 segments (ntg=q*9+s). Per segment: mega-D's verbatim BK=64
// K-loop on 256x256 output = A[256xK] x [G128 || U128]; waves (wr, bh, bq):
// bh=0 accumulates G, bh=1 accumulates U of the SAME 128 cols; single acc set
// per wave (128 VGPR). Footer: u-waves dump acc to LDS (rotation layout:
// 8-way = b128 floor, no excess conflicts), barrier, g-waves stream
// {read u, silu(g)*u*coef, store T}; stores drain under next prologue's
// counted WAITV4 (oldest-first vmcnt queue).
#define STAGE_A8(tile, hf)                                                     \
  do {                                                                         \
    const f16* g_ = Abase + (size_t)((hf) * 128) * 1024 + (tile) * 64 + aVoff; \
    f16* d_ = &lds[(2 * ((tile) & 1) + (hf)) * 8192 + w * 512];                \
    GLL16(g_, d_);                                                             \
    GLL16(g_ + (size_t)64 * 1024, d_ + 4096);                                  \
  } while (0)
#define STAGE_G8(tile)                                                         \
  do {                                                                         \
    const f16* g_ = Gbase + (tile) * 64 + aVoff;                               \
    f16* d_ = &lds[32768 + (2 * ((tile) & 1)) * 8192 + w * 512];               \
    GLL16(g_, d_);                                                             \
    GLL16(g_ + (size_t)64 * 1024, d_ + 4096);                                  \
  } while (0)
#define STAGE_U8(tile)                                                         \
  do {                                                                         \
    const f16* g_ = Ubase + (tile) * 64 + aVoff;                               \
    f16* d_ = &lds[32768 + (2 * ((tile) & 1) + 1) * 8192 + w * 512];           \
    GLL16(g_, d_);                                                             \
    GLL16(g_ + (size_t)64 * 1024, d_ + 4096);                                  \
  } while (0)

#define RD_A8(rh, buf)                                                         \
  do {                                                                         \
    const f16* p_ = &lds[(2 * (buf) + wr) * 8192 + (rh) * 4096];               \
    aFd[0][0] = *(const f16x8*)(p_ + 0 * 1024 + vR0);                          \
    aFd[0][1] = *(const f16x8*)(p_ + 0 * 1024 + vR1);                          \
    aFd[1][0] = *(const f16x8*)(p_ + 1 * 1024 + vR0);                          \
    aFd[1][1] = *(const f16x8*)(p_ + 1 * 1024 + vR1);                          \
    aFd[2][0] = *(const f16x8*)(p_ + 2 * 1024 + vR0);                          \
    aFd[2][1] = *(const f16x8*)(p_ + 2 * 1024 + vR1);                          \
    aFd[3][0] = *(const f16x8*)(p_ + 3 * 1024 + vR0);                          \
    aFd[3][1] = *(const f16x8*)(p_ + 3 * 1024 + vR1);                          \
  } while (0)
#define RD_B8(ch, buf)                                                         \
  do {                                                                         \
    const f16* p_ = &lds[32768 + (2 * (buf) + bh) * 8192 + bq * 4096 +         \
                         (ch) * 2 * 1024];                                     \
    bFd[(ch) * 2][0] = *(const f16x8*)(p_ + vR0);                              \
    bFd[(ch) * 2][1] = *(const f16x8*)(p_ + vR1);                              \
    bFd[(ch) * 2 + 1][0] = *(const f16x8*)(p_ + 1024 + vR0);                   \
    bFd[(ch) * 2 + 1][1] = *(const f16x8*)(p_ + 1024 + vR1);                   \
  } while (0)

#define MFMA8(rh, ch)                                                          \
  do {                                                                         \
    __builtin_amdgcn_s_setprio(1);                                             \
    _Pragma("unroll") for (int rt = 0; rt < 4; ++rt)                           \
        _Pragma("unroll") for (int ct = 0; ct < 2; ++ct)                       \
        _Pragma("unroll") for (int ks = 0; ks < 2; ++ks)                       \
            acc[(rh) * 4 + rt][(ch) * 2 + ct] =                                \
        __builtin_amdgcn_mfma_f32_16x16x32_f16(                                \
            aFd[rt][ks], bFd[(ch) * 2 + ct][ks],                               \
            acc[(rh) * 4 + rt][(ch) * 2 + ct], 0, 0, 0);                       \
    __builtin_amdgcn_s_setprio(0);                                             \
    __builtin_amdgcn_sched_barrier(0);                                         \
  } while (0)

__global__ __launch_bounds__(512, 2) void gemmUG8_kernel(
    const f16* __restrict__ A, const f16* __restrict__ Bg,
    const f16* __restrict__ Bu, f16* __restrict__ T,
    const float* __restrict__ gate, const float* __restrict__ sgp) {
  __shared__ __align__(16) f16 lds[65536];  // 128 KiB

  int xcd = blockIdx.x & 7;
  int idx = blockIdx.x >> 3;
  int mt = idx & 7;                // 0..7 (256 rows)
  int q = xcd * 4 + (idx >> 3);    // 0..31; XCD owns contiguous ntg range

  int t = threadIdx.x, w = t >> 6, l = t & 63;
  int wr = w >> 2, wc = w & 3;
  int bh = wc >> 1, bq = wc & 1;   // bh=0 -> G wave, bh=1 -> U wave

  int scol = (((l & 7) ^ ((l >> 3) & 7)) * 8);
  size_t aVoff = (size_t)(w * 8 + (l >> 3)) * 1024 + scol;
  const f16* Abase = A + (size_t)mt * 256 * 1024;

  int vR0 = (l & 15) * 64 + (((l >> 4) * 8) ^ ((l & 7) * 8));
  int vR1 = (l & 15) * 64 + ((32 + (l >> 4) * 8) ^ ((l & 7) * 8));

  f16x8 aFd[4][2], bFd[4][2];
  f32x4 acc[8][4] = {};

  int r0 = (l >> 4) * 4, c0 = l & 15;
  int rowb = mt * 256 + wr * 128;
  float sgv = sgp[mt >> 2];
  float* xf = (float*)lds;

#pragma unroll 1
  for (int s = 0; s < 9; ++s) {
    int ntg = q * 9 + s;
    int slot = ntg >> 5;
    int ntl = ntg & 31;
    const f16* Gbase = Bg + (size_t)slot * 4194304 + (size_t)ntl * 128 * 1024;
    const f16* Ubase = Bu + (size_t)slot * 4194304 + (size_t)ntl * 128 * 1024;

    // prologue (mirrors mega-D): tile0 {G,U,A}, tile1 {G,U}; wait 8 oldest
    // (for s>0 this also drains prior segment's T-stores first: oldest in q)
    STAGE_G8(0); STAGE_U8(0);
    STAGE_A8(0, 0); STAGE_A8(0, 1);
    STAGE_G8(1); STAGE_U8(1);
    WAITV4;
    BARX;

#pragma unroll 1
    for (int it = 0; it < 7; ++it) {   // K-tiles 0..13
      int t1 = 2 * it + 1, t2 = 2 * it + 2, t3 = 2 * it + 3;
      RD_A8(0, 0); RD_B8(0, 0); STAGE_A8(t1, 0);
      BARX; WAITL0; MFMA8(0, 0); BARX;
      RD_B8(1, 0); STAGE_A8(t1, 1);
      BARX; WAITL0; MFMA8(0, 1); BARX;
      RD_A8(1, 0); STAGE_G8(t2);
      BARX; WAITL0; MFMA8(1, 0); BARX;
      STAGE_U8(t2);
      BARX; MFMA8(1, 1); WAITV4; BARX;
      RD_A8(0, 1); RD_B8(0, 1); STAGE_A8(t2, 0);
      BARX; WAITL0; MFMA8(0, 0); BARX;
      RD_B8(1, 1); STAGE_A8(t2, 1);
      BARX; WAITL0; MFMA8(0, 1); BARX;
      RD_A8(1, 1); STAGE_G8(t3);
      BARX; WAITL0; MFMA8(1, 0); BARX;
      STAGE_U8(t3);
      BARX; MFMA8(1, 1); WAITV4; BARX;
    }
    // peeled: tiles 14 (buf0), 15 (buf1); no overrun stages
    RD_A8(0, 0); RD_B8(0, 0); STAGE_A8(15, 0);
    BARX; WAITL0; MFMA8(0, 0); BARX;
    RD_B8(1, 0); STAGE_A8(15, 1);
    BARX; WAITL0; MFMA8(0, 1); BARX;
    RD_A8(1, 0);
    BARX; WAITL0; MFMA8(1, 0); BARX;
    BARX; MFMA8(1, 1); WAITV0; BARX;
    RD_A8(0, 1); RD_B8(0, 1);
    BARX; WAITL0; MFMA8(0, 0); BARX;
    RD_B8(1, 1);
    BARX; WAITL0; MFMA8(0, 1); BARX;
    RD_A8(1, 1);
    BARX; WAITL0; MFMA8(1, 0); BARX;   // after this barrier no wave reads
    MFMA8(1, 1);                       // staging LDS (register-only MFMAs)

    // ---- exchange: u-waves dump acc (rotation layout: lane l, vec idx
    // (rt*4+ct) at region + l*128 + ((idx+l)&31)*4 floats -> each b128
    // wave-op spreads over 8 bank-quads = floor, no excess conflicts) ----
    if (bh == 1) {
      float* wb = xf + (wr * 2 + bq) * 8192 + l * 128;
#pragma unroll
      for (int rt = 0; rt < 8; ++rt)
#pragma unroll
        for (int ct = 0; ct < 4; ++ct) {
          int idx2 = rt * 4 + ct;
          *(f32x4*)(wb + (((idx2 + l) & 31) * 4)) = acc[rt][ct];
        }
    }
    WAITL0;  // writes committed before barrier
    BARX;
    // ---- g-waves: stream read u, combine, store T ----
    if (bh == 0) {
      const float* rb = xf + (wr * 2 + bq) * 8192 + l * 128;
      size_t colb = (size_t)ntg * 128 + bq * 64;
      float coef = (slot < 8) ? (1.f - sgv) * gate[(mt >> 2) * 8 + slot] : sgv;
#pragma unroll
      for (int rt = 0; rt < 8; ++rt) {
#pragma unroll
        for (int ct = 0; ct < 4; ++ct) {
          int idx2 = rt * 4 + ct;
          f32x4 uv = *(const f32x4*)(rb + (((idx2 + l) & 31) * 4));
#pragma unroll
          for (int j = 0; j < 4; ++j) {
            float g = acc[rt][ct][j];
            T[(size_t)(rowb + rt * 16 + r0 + j) * 36864 + colb + ct * 16 +
              c0] = (f16)(g / (1.f + __expf(-g)) * uv[j] * coef);
          }
        }
      }
    }
    WAITL0;  // all exchange reads complete before LDS is restaged
    BARX;
    // reset accumulators for next segment
#pragma unroll
    for (int rt = 0; rt < 8; ++rt)
#pragma unroll
      for (int ct = 0; ct < 4; ++ct)
        acc[rt][ct] = (f32x4){0.f, 0.f, 0.f, 0.f};
  }
}

// =================== 256x256 8-phase GEMM (mega down-proj) ==================
#define STAGE_A(tile, hf)                                                      \
  do {                                                                         \
    const f16* g_ = Abase + (size_t)((hf) * 128) * LD + (tile) * 64 + aVoff;   \
    f16* d_ = &lds[(2 * ((tile) & 1) + (hf)) * 8192 + w * 512];                \
    GLL16(g_, d_);                                                             \
    GLL16(g_ + (size_t)64 * LD, d_ + 4096);                                    \
  } while (0)
#define STAGE_B(tile, hf)                                                      \
  do {                                                                         \
    const f16* g_ = Bbase + (size_t)((hf) * 128) * LD + (tile) * 64 + aVoff;   \
    f16* d_ = &lds[32768 + (2 * ((tile) & 1) + (hf)) * 8192 + w * 512];        \
    GLL16(g_, d_);                                                             \
    GLL16(g_ + (size_t)64 * LD, d_ + 4096);                                    \
  } while (0)

#define RD_A(rh, buf)                                                          \
  do {                                                                         \
    const f16* p_ = &lds[(2 * (buf) + wr) * 8192 + (rh) * 4096];               \
    aFd[0][0] = *(const f16x8*)(p_ + 0 * 1024 + vR0);                          \
    aFd[0][1] = *(const f16x8*)(p_ + 0 * 1024 + vR1);                          \
    aFd[1][0] = *(const f16x8*)(p_ + 1 * 1024 + vR0);                          \
    aFd[1][1] = *(const f16x8*)(p_ + 1 * 1024 + vR1);                          \
    aFd[2][0] = *(const f16x8*)(p_ + 2 * 1024 + vR0);                          \
    aFd[2][1] = *(const f16x8*)(p_ + 2 * 1024 + vR1);                          \
    aFd[3][0] = *(const f16x8*)(p_ + 3 * 1024 + vR0);                          \
    aFd[3][1] = *(const f16x8*)(p_ + 3 * 1024 + vR1);                          \
  } while (0)
#define RD_B(ch, buf)                                                          \
  do {                                                                         \
    const f16* p_ = &lds[32768 + (2 * (buf) + bh) * 8192 + bq * 4096 +         \
                         (ch) * 2 * 1024];                                     \
    bFd[(ch) * 2][0] = *(const f16x8*)(p_ + vR0);                              \
    bFd[(ch) * 2][1] = *(const f16x8*)(p_ + vR1);                              \
    bFd[(ch) * 2 + 1][0] = *(const f16x8*)(p_ + 1024 + vR0);                   \
    bFd[(ch) * 2 + 1][1] = *(const f16x8*)(p_ + 1024 + vR1);                   \
  } while (0)

#define MFMA16(rh, ch)                                                         \
  do {                                                                         \
    __builtin_amdgcn_s_setprio(1);                                             \
    _Pragma("unroll") for (int rt = 0; rt < 4; ++rt)                           \
        _Pragma("unroll") for (int ct = 0; ct < 2; ++ct)                       \
        _Pragma("unroll") for (int ks = 0; ks < 2; ++ks)                       \
            acc[(rh) * 4 + rt][(ch) * 2 + ct] =                                \
        __builtin_amdgcn_mfma_f32_16x16x32_f16(                                \
            aFd[rt][ks], bFd[(ch) * 2 + ct][ks],                               \
            acc[(rh) * 4 + rt][(ch) * 2 + ct], 0, 0, 0);                       \
    __builtin_amdgcn_s_setprio(0);                                             \
    __builtin_amdgcn_sched_barrier(0);                                         \
  } while (0)

__global__ __launch_bounds__(512, 2) void gemmD_kernel(
    const f16* __restrict__ A, const f16* __restrict__ B,
    f16* __restrict__ P) {
  constexpr size_t LD = 36864;
  constexpr int NTILES = 72;
  __shared__ __align__(16) f16 lds[65536];

  int wg = (blockIdx.x & 7) * 32 + (blockIdx.x >> 3);
  int kpart = wg >> 5, mt = (wg >> 2) & 7, nt = wg & 3;

  int t = threadIdx.x, w = t >> 6, l = t & 63;
  int wr = w >> 2, wc = w & 3;
  int bh = wc >> 1, bq = wc & 1;

  int scol = (((l & 7) ^ ((l >> 3) & 7)) * 8);
  size_t stRow = (size_t)(w * 8 + (l >> 3)) * LD;
  size_t aVoff = stRow + scol;
  const f16* Abase = A + (size_t)mt * 256 * LD + (size_t)kpart * 4608;
  const f16* Bbase = B + (size_t)nt * 256 * LD + (size_t)kpart * 4608;

  int vR0 = (l & 15) * 64 + (((l >> 4) * 8) ^ ((l & 7) * 8));
  int vR1 = (l & 15) * 64 + ((32 + (l >> 4) * 8) ^ ((l & 7) * 8));

  f16x8 aFd[4][2], bFd[4][2];
  f32x4 acc[8][4] = {};

  STAGE_B(0, 0); STAGE_B(0, 1);
  STAGE_A(0, 0); STAGE_A(0, 1);
  STAGE_B(1, 0); STAGE_B(1, 1);
  WAITV4;
  BARX;

#pragma unroll 1
  for (int it = 0; it < NTILES / 2 - 1; ++it) {
    int t1 = 2 * it + 1, t2 = 2 * it + 2, t3 = 2 * it + 3;
    RD_A(0, 0); RD_B(0, 0); STAGE_A(t1, 0);
    BARX; WAITL0; MFMA16(0, 0); BARX;
    RD_B(1, 0); STAGE_A(t1, 1);
    BARX; WAITL0; MFMA16(0, 1); BARX;
    RD_A(1, 0); STAGE_B(t2, 0);
    BARX; WAITL0; MFMA16(1, 0); BARX;
    STAGE_B(t2, 1);
    BARX; MFMA16(1, 1); WAITV4; BARX;
    RD_A(0, 1); RD_B(0, 1); STAGE_A(t2, 0);
    BARX; WAITL0; MFMA16(0, 0); BARX;
    RD_B(1, 1); STAGE_A(t2, 1);
    BARX; WAITL0; MFMA16(0, 1); BARX;
    RD_A(1, 1); STAGE_B(t3, 0);
    BARX; WAITL0; MFMA16(1, 0); BARX;
    STAGE_B(t3, 1);
    BARX; MFMA16(1, 1); WAITV4; BARX;
  }
  RD_A(0, 0); RD_B(0, 0); STAGE_A(NTILES - 1, 0);
  BARX; WAITL0; MFMA16(0, 0); BARX;
  RD_B(1, 0); STAGE_A(NTILES - 1, 1);
  BARX; WAITL0; MFMA16(0, 1); BARX;
  RD_A(1, 0);
  BARX; WAITL0; MFMA16(1, 0); BARX;
  BARX; MFMA16(1, 1); WAITV0; BARX;
  RD_A(0, 1); RD_B(0, 1);
  BARX; WAITL0; MFMA16(0, 0); BARX;
  RD_B(1, 1);
  BARX; WAITL0; MFMA16(0, 1); BARX;
  RD_A(1, 1);
  BARX; WAITL0; MFMA16(1, 0); BARX;
  MFMA16(1, 1);

  int r0 = (l >> 4) * 4, c0 = l & 15;
  size_t base = ((size_t)kpart << 21);
  int rowbase = mt * 256 + wr * 128;
  int colbase = nt * 256 + wc * 64;
#pragma unroll
  for (int rt = 0; rt < 8; ++rt)
#pragma unroll
    for (int ct = 0; ct < 4; ++ct)
#pragma unroll
      for (int j = 0; j < 4; ++j)
        P[base + (size_t)(rowbase + rt * 16 + r0 + j) * 1024 + colbase +
          ct * 16 + c0] = (f16)acc[rt][ct][j];
}

// ---------------- sum 8 f16 split-K partials -> fp32 out --------------------
__global__ void reduce8_kernel(const f16* __restrict__ P,
                               float* __restrict__ out, int n4) {
  int i = blockIdx.x * blockDim.x + threadIdx.x;
  if (i < n4) {
    f32x4 s = {0.f, 0.f, 0.f, 0.f};
#pragma unroll
    for (int e = 0; e < 8; ++e) {
      f16x4 v = reinterpret_cast<const f16x4*>(P + ((size_t)e << 21))[i];
      s[0] += (float)v[0]; s[1] += (float)v[1];
      s[2] += (float)v[2]; s[3] += (float)v[3];
    }
    reinterpret_cast<f32x4*>(out)[i] = s;
  }
}

extern "C" void kernel_launch(void* const* d_in, const int* in_sizes, int n_in,
                              void* d_out, int out_size, void* d_ws,
                              size_t ws_size, hipStream_t stream) {
  const float* h    = (const float*)d_in[0];
  const float* gate = (const float*)d_in[1];
  const float* sgp  = (const float*)d_in[2];
  const float* Wg   = (const float*)d_in[3];
  const float* Wu   = (const float*)d_in[4];
  const float* Wd   = (const float*)d_in[5];
  const float* Sg   = (const float*)d_in[6];
  const float* Su   = (const float*)d_in[7];
  const float* Sd   = (const float*)d_in[8];

  const size_t SZ_HB = 4194304;      // 2048*1024 f16
  const size_t SZ_W  = 75497472;     // 9*4096*1024 f16
  const size_t SZ_T  = 150994944;    // 2048*36864 f16
  const size_t SZ_P  = 33554432;     // 8*2048*1024 f16
  char* ws = (char*)d_ws;
  f16*   hb  = (f16*)(ws);
  f16*   WgT = (f16*)(ws + SZ_HB);
  f16*   WuT = (f16*)(ws + SZ_HB + SZ_W);
  f16*   WdT = (f16*)(ws + SZ_HB + 2 * SZ_W);  // [1024][36864] mega
  f16*   T   = (f16*)(ws + SZ_HB + 3 * SZ_W);
  f16*   P   = (f16*)(ws + SZ_HB + 3 * SZ_W + SZ_T);
  size_t need = SZ_HB + 3 * SZ_W + SZ_T + SZ_P;
  if (ws_size < need) {
    fprintf(stderr, "kernel_launch: ws too small (%zu < %zu)\n", ws_size, need);
    return;
  }
  float* out = (float*)d_out;

  cvt_f32_f16_kernel<<<2048, 256, 0, stream>>>(h, hb, 524288);
  tr_cvt2_kernel<<<dim3(64, 16, 9), 256, 0, stream>>>(
      Wg, Sg, WgT, 4096ull * 1024, 4096, 1024, 8);
  tr_cvt2_kernel<<<dim3(64, 16, 9), 256, 0, stream>>>(
      Wu, Su, WuT, 4096ull * 1024, 4096, 1024, 8);
  tr_cvt2_kernel<<<dim3(16, 64, 9), 256, 0, stream>>>(
      Wd, Sd, WdT, 4096, 1024, 36864, 8);

  gemmUG8_kernel<<<256, 512, 0, stream>>>(hb, WgT, WuT, T, gate, sgp);
  gemmD_kernel<<<256, 512, 0, stream>>>(T, WdT, P);
  reduce8_kernel<<<2048, 256, 0, stream>>>(P, out, 524288);
}

// Round 13
// 555.246 us; speedup vs baseline: 1.2679x; 1.2679x over previous
//
#include <hip/hip_runtime.h>
#include <cstdio>
#include <cstdint>

typedef _Float16 f16;
typedef _Float16 f16x4 __attribute__((ext_vector_type(4)));
typedef _Float16 f16x8 __attribute__((ext_vector_type(8)));
typedef float f32x4 __attribute__((ext_vector_type(4)));

#define GLL16(gp, lp)                                                          \
  __builtin_amdgcn_global_load_lds(                                            \
      (const __attribute__((address_space(1))) void*)(gp),                     \
      (__attribute__((address_space(3))) void*)(lp), 16, 0, 0)

#define BARX __builtin_amdgcn_s_barrier()
#define WAITV8 { asm volatile("s_waitcnt vmcnt(8)" ::: "memory"); __builtin_amdgcn_sched_barrier(0); }
#define WAITV4 { asm volatile("s_waitcnt vmcnt(4)" ::: "memory"); __builtin_amdgcn_sched_barrier(0); }
#define WAITV0 { asm volatile("s_waitcnt vmcnt(0)" ::: "memory"); __builtin_amdgcn_sched_barrier(0); }
#define WAITL0 { asm volatile("s_waitcnt lgkmcnt(0)" ::: "memory"); __builtin_amdgcn_sched_barrier(0); }

// ---------------- fp32 -> fp16 elementwise (h) ----------------
__global__ void cvt_f32_f16_kernel(const float* __restrict__ in,
                                   f16* __restrict__ out, int n4) {
  int i = blockIdx.x * blockDim.x + threadIdx.x;
  if (i < n4) {
    f32x4 v = reinterpret_cast<const f32x4*>(in)[i];
    f16x4 o;
    o[0] = (f16)v[0]; o[1] = (f16)v[1]; o[2] = (f16)v[2]; o[3] = (f16)v[3];
    reinterpret_cast<f16x4*>(out)[i] = o;
  }
}

// ------- fp32 [R][C] -> fp16 transposed, 64x64 tiles, coalesced stores ------
__global__ void tr_cvt2_kernel(const float* __restrict__ inA,
                               const float* __restrict__ inB,
                               f16* __restrict__ out, size_t slotOff,
                               int C, size_t OS, int nA) {
  int slot = blockIdx.z;
  const float* src = (slot < nA) ? inA + (size_t)slot * 64 * gridDim.y * C : inB;
  f16* dst = out + (size_t)slot * slotOff;
  __shared__ f16 tl[4096];
  int t = threadIdx.x;
  int r0 = blockIdx.y * 64, c0 = blockIdx.x * 64;
  int br = (t >> 4) * 4, bc = (t & 15) * 4;
  f32x4 v[4];
#pragma unroll
  for (int i = 0; i < 4; ++i)
    v[i] = *(const f32x4*)&src[(size_t)(r0 + br + i) * C + c0 + bc];
#pragma unroll
  for (int cc = 0; cc < 4; ++cc) {
    int c = bc + cc;
    f16x4 o;
    o[0] = (f16)v[0][cc]; o[1] = (f16)v[1][cc];
    o[2] = (f16)v[2][cc]; o[3] = (f16)v[3][cc];
    *(f16x4*)&tl[c * 64 + (br ^ ((c & 7) * 8))] = o;
  }
  __syncthreads();
  int rw = (t & 7) * 8, cw = t >> 3;
#pragma unroll
  for (int j = 0; j < 2; ++j) {
    int c = cw + j * 32;
    f16x8 o = *(const f16x8*)&tl[c * 64 + (rw ^ ((c & 7) * 8))];
    *(f16x8*)&dst[(size_t)(c0 + c) * OS + r0 + rw] = o;
  }
}

// ============ fused UG (R6 best: fat 2-phase): T = silu(h@Wg)*(h@Wu)*coef ===
// BM=256 BN=128 BK=64, 512 thr / 8 waves (4M x 2N), per-wave 64x64 dual-acc.
// 2 barriers/K-tile, counted vmcnt(8), 2-tile prefetch depth.
// LDS 128KB: per buf {A 32KB at buf*16384(f16); Bg 8KB + Bu 8KB at
// 32768+buf*16384}. Swizzle: k-group slot = kq ^ (row&7) (8 groups of 8 f16).
#define STAGE_T(NB, TILE)                                                      \
  do {                                                                         \
    const f16* a_ = aS + (size_t)(TILE) * 64;                                  \
    f16* da_ = &lds[(NB) * 16384 + ldsT];                                      \
    GLL16(a_, da_); GLL16(a_ + 65536, da_ + 4096);                             \
    GLL16(a_ + 131072, da_ + 8192); GLL16(a_ + 196608, da_ + 12288);           \
    const f16* g_ = gS + (size_t)(TILE) * 64;                                  \
    f16* dg_ = &lds[32768 + (NB) * 16384 + ldsT];                              \
    GLL16(g_, dg_); GLL16(g_ + 65536, dg_ + 4096);                             \
    const f16* u_ = uS + (size_t)(TILE) * 64;                                  \
    GLL16(u_, dg_ + 8192); GLL16(u_ + 65536, dg_ + 12288);                     \
  } while (0)

#define RD3(BUF, VK)                                                           \
  do {                                                                         \
    const f16* pa_ = &lds[(BUF) * 16384 + wr * 4096 + vRow + (VK)];            \
    aF[0] = *(const f16x8*)(pa_);                                              \
    aF[1] = *(const f16x8*)(pa_ + 1024);                                       \
    aF[2] = *(const f16x8*)(pa_ + 2048);                                       \
    aF[3] = *(const f16x8*)(pa_ + 3072);                                       \
    const f16* pg_ = &lds[32768 + (BUF) * 16384 + wc * 4096 + vRow + (VK)];    \
    bG[0] = *(const f16x8*)(pg_);                                              \
    bG[1] = *(const f16x8*)(pg_ + 1024);                                       \
    bG[2] = *(const f16x8*)(pg_ + 2048);                                       \
    bG[3] = *(const f16x8*)(pg_ + 3072);                                       \
    const f16* pu_ = pg_ + 8192;                                               \
    bU[0] = *(const f16x8*)(pu_);                                              \
    bU[1] = *(const f16x8*)(pu_ + 1024);                                       \
    bU[2] = *(const f16x8*)(pu_ + 2048);                                       \
    bU[3] = *(const f16x8*)(pu_ + 3072);                                       \
  } while (0)

#define MFMA32()                                                               \
  do {                                                                         \
    __builtin_amdgcn_s_setprio(1);                                             \
    _Pragma("unroll") for (int mi = 0; mi < 4; ++mi)                           \
        _Pragma("unroll") for (int ni = 0; ni < 4; ++ni) {                     \
      ag[mi][ni] = __builtin_amdgcn_mfma_f32_16x16x32_f16(aF[mi], bG[ni],      \
                                                          ag[mi][ni], 0, 0, 0);\
      au[mi][ni] = __builtin_amdgcn_mfma_f32_16x16x32_f16(aF[mi], bU[ni],      \
                                                          au[mi][ni], 0, 0, 0);\
    }                                                                          \
    __builtin_amdgcn_s_setprio(0);                                             \
    __builtin_amdgcn_sched_barrier(0);                                         \
  } while (0)

// Per K-tile: ph1 {RD k0; lgkm0; MFMA} (no barrier); ph2 {RD k1; lgkm0; BARX;
// stage tile+2 into cur (safe: all waves' reads in regs); MFMA; WV; BARX}.
#define BODY4(BUF, TILE, DOST, WV)                                             \
  do {                                                                         \
    RD3(BUF, vK0);                                                             \
    WAITL0;                                                                    \
    MFMA32();                                                                  \
    RD3(BUF, vK1);                                                             \
    WAITL0;                                                                    \
    BARX;                                                                      \
    if (DOST) { STAGE_T(BUF, TILE); }                                          \
    MFMA32();                                                                  \
    WV;                                                                        \
    BARX;                                                                      \
  } while (0)

__global__ __launch_bounds__(512, 2) void gemmUG3_kernel(
    const f16* __restrict__ A, const f16* __restrict__ Bg,
    const f16* __restrict__ Bu, f16* __restrict__ T,
    const float* __restrict__ gate, const float* __restrict__ sgp) {
  __shared__ __align__(16) f16 lds[65536];  // 128 KiB

  // XCD-chunked: logical = xcd*288 + i; mt fastest within chunk.
  int lgl = (blockIdx.x & 7) * 288 + (blockIdx.x >> 3);
  int mt = lgl & 7;            // 0..7   (256 rows each)
  int ntg = lgl >> 3;          // 0..287 (128 cols each)
  int slot = ntg >> 5;         // 0..8

  int t = threadIdx.x, w = t >> 6, l = t & 63;
  int wr = w >> 1, wc = w & 1;  // wave grid 4M x 2N

  // staging: thread t covers row (t>>3)+i*64, k-group slot t&7 (src XOR'd)
  int kqs = (((t & 7) ^ ((t >> 3) & 7)) * 8);
  const f16* aS = A + (size_t)(mt * 256 + (t >> 3)) * 1024 + kqs;
  const f16* gS = Bg + (size_t)slot * 4194304 +
                  (size_t)((ntg & 31) * 128 + (t >> 3)) * 1024 + kqs;
  const f16* uS = Bu + (size_t)slot * 4194304 +
                  (size_t)((ntg & 31) * 128 + (t >> 3)) * 1024 + kqs;
  int ldsT = t * 8;

  // frag read offsets: row=(l&15), k-slot = (ks*4 + (l>>4)) ^ (l&7)
  int vRow = (l & 15) * 64;
  int vK0 = (((l >> 4) ^ (l & 7))) * 8;
  int vK1 = (((4 + (l >> 4)) ^ (l & 7))) * 8;

  f16x8 aF[4], bG[4], bU[4];
  f32x4 ag[4][4] = {}, au[4][4] = {};

  // prologue: stage tiles 0,1 -> bufs 0,1; wait tile0 only (8 still out)
  STAGE_T(0, 0);
  STAGE_T(1, 1);
  WAITV8; BARX;

#pragma unroll 1
  for (int it = 0; it < 7; ++it) {
    BODY4(0, 2 * it + 2, 1, WAITV8);
    BODY4(1, 2 * it + 3, 1, WAITV8);
  }
  BODY4(0, 0, 0, WAITV0);   // tile 14; drain tile-15 loads
  BODY4(1, 0, 0, {});       // tile 15

  // epilogue: C/D col=lane&15, row=(lane>>4)*4+j
  int r0 = (l >> 4) * 4, c0 = l & 15;
  int rowb = mt * 256 + wr * 64;
  size_t colb = (size_t)ntg * 128 + wc * 64;
  int b = mt >> 2;
  float s = sgp[b];
  float coef = (slot < 8) ? (1.f - s) * gate[b * 8 + slot] : s;
#pragma unroll
  for (int mi = 0; mi < 4; ++mi) {
#pragma unroll
    for (int ni = 0; ni < 4; ++ni) {
#pragma unroll
      for (int j = 0; j < 4; ++j) {
        float g = ag[mi][ni][j];
        float u = au[mi][ni][j];
        T[(size_t)(rowb + mi * 16 + r0 + j) * 36864 + colb + ni * 16 + c0] =
            (f16)(g / (1.f + __expf(-g)) * u * coef);
      }
    }
  }
}

// =================== 256x256 8-phase GEMM (mega down-proj, f16 P) ===========
#define STAGE_A(tile, hf)                                                      \
  do {                                                                         \
    const f16* g_ = Abase + (size_t)((hf) * 128) * LD + (tile) * 64 + aVoff;   \
    f16* d_ = &lds[(2 * ((tile) & 1) + (hf)) * 8192 + w * 512];                \
    GLL16(g_, d_);                                                             \
    GLL16(g_ + (size_t)64 * LD, d_ + 4096);                                    \
  } while (0)
#define STAGE_B(tile, hf)                                                      \
  do {                                                                         \
    const f16* g_ = Bbase + (size_t)((hf) * 128) * LD + (tile) * 64 + aVoff;   \
    f16* d_ = &lds[32768 + (2 * ((tile) & 1) + (hf)) * 8192 + w * 512];        \
    GLL16(g_, d_);                                                             \
    GLL16(g_ + (size_t)64 * LD, d_ + 4096);                                    \
  } while (0)

#define RD_A(rh, buf)                                                          \
  do {                                                                         \
    const f16* p_ = &lds[(2 * (buf) + wr) * 8192 + (rh) * 4096];               \
    aFd[0][0] = *(const f16x8*)(p_ + 0 * 1024 + vR0);                          \
    aFd[0][1] = *(const f16x8*)(p_ + 0 * 1024 + vR1);                          \
    aFd[1][0] = *(const f16x8*)(p_ + 1 * 1024 + vR0);                          \
    aFd[1][1] = *(const f16x8*)(p_ + 1 * 1024 + vR1);                          \
    aFd[2][0] = *(const f16x8*)(p_ + 2 * 1024 + vR0);                          \
    aFd[2][1] = *(const f16x8*)(p_ + 2 * 1024 + vR1);                          \
    aFd[3][0] = *(const f16x8*)(p_ + 3 * 1024 + vR0);                          \
    aFd[3][1] = *(const f16x8*)(p_ + 3 * 1024 + vR1);                          \
  } while (0)
#define RD_B(ch, buf)                                                          \
  do {                                                                         \
    const f16* p_ = &lds[32768 + (2 * (buf) + bh) * 8192 + bq * 4096 +         \
                         (ch) * 2 * 1024];                                     \
    bFd[(ch) * 2][0] = *(const f16x8*)(p_ + vR0);                              \
    bFd[(ch) * 2][1] = *(const f16x8*)(p_ + vR1);                              \
    bFd[(ch) * 2 + 1][0] = *(const f16x8*)(p_ + 1024 + vR0);                   \
    bFd[(ch) * 2 + 1][1] = *(const f16x8*)(p_ + 1024 + vR1);                   \
  } while (0)

#define MFMA16(rh, ch)                                                         \
  do {                                                                         \
    __builtin_amdgcn_s_setprio(1);                                             \
    _Pragma("unroll") for (int rt = 0; rt < 4; ++rt)                           \
        _Pragma("unroll") for (int ct = 0; ct < 2; ++ct)                       \
        _Pragma("unroll") for (int ks = 0; ks < 2; ++ks)                       \
            acc[(rh) * 4 + rt][(ch) * 2 + ct] =                                \
        __builtin_amdgcn_mfma_f32_16x16x32_f16(                                \
            aFd[rt][ks], bFd[(ch) * 2 + ct][ks],                               \
            acc[(rh) * 4 + rt][(ch) * 2 + ct], 0, 0, 0);                       \
    __builtin_amdgcn_s_setprio(0);                                             \
    __builtin_amdgcn_sched_barrier(0);                                         \
  } while (0)

__global__ __launch_bounds__(512, 2) void gemmD_kernel(
    const f16* __restrict__ A, const f16* __restrict__ B,
    f16* __restrict__ P) {
  constexpr size_t LD = 36864;
  constexpr int NTILES = 72;
  __shared__ __align__(16) f16 lds[65536];

  int wg = (blockIdx.x & 7) * 32 + (blockIdx.x >> 3);
  int kpart = wg >> 5, mt = (wg >> 2) & 7, nt = wg & 3;

  int t = threadIdx.x, w = t >> 6, l = t & 63;
  int wr = w >> 2, wc = w & 3;
  int bh = wc >> 1, bq = wc & 1;

  int scol = (((l & 7) ^ ((l >> 3) & 7)) * 8);
  size_t stRow = (size_t)(w * 8 + (l >> 3)) * LD;
  size_t aVoff = stRow + scol;
  const f16* Abase = A + (size_t)mt * 256 * LD + (size_t)kpart * 4608;
  const f16* Bbase = B + (size_t)nt * 256 * LD + (size_t)kpart * 4608;

  int vR0 = (l & 15) * 64 + (((l >> 4) * 8) ^ ((l & 7) * 8));
  int vR1 = (l & 15) * 64 + ((32 + (l >> 4) * 8) ^ ((l & 7) * 8));

  f16x8 aFd[4][2], bFd[4][2];
  f32x4 acc[8][4] = {};

  STAGE_B(0, 0); STAGE_B(0, 1);
  STAGE_A(0, 0); STAGE_A(0, 1);
  STAGE_B(1, 0); STAGE_B(1, 1);
  WAITV4;
  BARX;

#pragma unroll 1
  for (int it = 0; it < NTILES / 2 - 1; ++it) {
    int t1 = 2 * it + 1, t2 = 2 * it + 2, t3 = 2 * it + 3;
    RD_A(0, 0); RD_B(0, 0); STAGE_A(t1, 0);
    BARX; WAITL0; MFMA16(0, 0); BARX;
    RD_B(1, 0); STAGE_A(t1, 1);
    BARX; WAITL0; MFMA16(0, 1); BARX;
    RD_A(1, 0); STAGE_B(t2, 0);
    BARX; WAITL0; MFMA16(1, 0); BARX;
    STAGE_B(t2, 1);
    BARX; MFMA16(1, 1); WAITV4; BARX;
    RD_A(0, 1); RD_B(0, 1); STAGE_A(t2, 0);
    BARX; WAITL0; MFMA16(0, 0); BARX;
    RD_B(1, 1); STAGE_A(t2, 1);
    BARX; WAITL0; MFMA16(0, 1); BARX;
    RD_A(1, 1); STAGE_B(t3, 0);
    BARX; WAITL0; MFMA16(1, 0); BARX;
    STAGE_B(t3, 1);
    BARX; MFMA16(1, 1); WAITV4; BARX;
  }
  RD_A(0, 0); RD_B(0, 0); STAGE_A(NTILES - 1, 0);
  BARX; WAITL0; MFMA16(0, 0); BARX;
  RD_B(1, 0); STAGE_A(NTILES - 1, 1);
  BARX; WAITL0; MFMA16(0, 1); BARX;
  RD_A(1, 0);
  BARX; WAITL0; MFMA16(1, 0); BARX;
  BARX; MFMA16(1, 1); WAITV0; BARX;
  RD_A(0, 1); RD_B(0, 1);
  BARX; WAITL0; MFMA16(0, 0); BARX;
  RD_B(1, 1);
  BARX; WAITL0; MFMA16(0, 1); BARX;
  RD_A(1, 1);
  BARX; WAITL0; MFMA16(1, 0); BARX;
  MFMA16(1, 1);

  int r0 = (l >> 4) * 4, c0 = l & 15;
  size_t base = ((size_t)kpart << 21);
  int rowbase = mt * 256 + wr * 128;
  int colbase = nt * 256 + wc * 64;
#pragma unroll
  for (int rt = 0; rt < 8; ++rt)
#pragma unroll
    for (int ct = 0; ct < 4; ++ct)
#pragma unroll
      for (int j = 0; j < 4; ++j)
        P[base + (size_t)(rowbase + rt * 16 + r0 + j) * 1024 + colbase +
          ct * 16 + c0] = (f16)acc[rt][ct][j];
}

// ---------------- sum 8 f16 split-K partials -> fp32 out --------------------
__global__ void reduce8_kernel(const f16* __restrict__ P,
                               float* __restrict__ out, int n4) {
  int i = blockIdx.x * blockDim.x + threadIdx.x;
  if (i < n4) {
    f32x4 s = {0.f, 0.f, 0.f, 0.f};
#pragma unroll
    for (int e = 0; e < 8; ++e) {
      f16x4 v = reinterpret_cast<const f16x4*>(P + ((size_t)e << 21))[i];
      s[0] += (float)v[0]; s[1] += (float)v[1];
      s[2] += (float)v[2]; s[3] += (float)v[3];
    }
    reinterpret_cast<f32x4*>(out)[i] = s;
  }
}

extern "C" void kernel_launch(void* const* d_in, const int* in_sizes, int n_in,
                              void* d_out, int out_size, void* d_ws,
                              size_t ws_size, hipStream_t stream) {
  const float* h    = (const float*)d_in[0];
  const float* gate = (const float*)d_in[1];
  const float* sgp  = (const float*)d_in[2];
  const float* Wg   = (const float*)d_in[3];
  const float* Wu   = (const float*)d_in[4];
  const float* Wd   = (const float*)d_in[5];
  const float* Sg   = (const float*)d_in[6];
  const float* Su   = (const float*)d_in[7];
  const float* Sd   = (const float*)d_in[8];

  const size_t SZ_HB = 4194304;      // 2048*1024 f16
  const size_t SZ_W  = 75497472;     // 9*4096*1024 f16
  const size_t SZ_T  = 150994944;    // 2048*36864 f16
  const size_t SZ_P  = 33554432;     // 8*2048*1024 f16
  char* ws = (char*)d_ws;
  f16*   hb  = (f16*)(ws);
  f16*   WgT = (f16*)(ws + SZ_HB);
  f16*   WuT = (f16*)(ws + SZ_HB + SZ_W);
  f16*   WdT = (f16*)(ws + SZ_HB + 2 * SZ_W);  // [1024][36864] mega
  f16*   T   = (f16*)(ws + SZ_HB + 3 * SZ_W);
  f16*   P   = (f16*)(ws + SZ_HB + 3 * SZ_W + SZ_T);
  size_t need = SZ_HB + 3 * SZ_W + SZ_T + SZ_P;
  if (ws_size < need) {
    fprintf(stderr, "kernel_launch: ws too small (%zu < %zu)\n", ws_size, need);
    return;
  }
  float* out = (float*)d_out;

  cvt_f32_f16_kernel<<<2048, 256, 0, stream>>>(h, hb, 524288);
  tr_cvt2_kernel<<<dim3(64, 16, 9), 256, 0, stream>>>(
      Wg, Sg, WgT, 4096ull * 1024, 4096, 1024, 8);
  tr_cvt2_kernel<<<dim3(64, 16, 9), 256, 0, stream>>>(
      Wu, Su, WuT, 4096ull * 1024, 4096, 1024, 8);
  tr_cvt2_kernel<<<dim3(16, 64, 9), 256, 0, stream>>>(
      Wd, Sd, WdT, 4096, 1024, 36864, 8);

  gemmUG3_kernel<<<2304, 512, 0, stream>>>(hb, WgT, WuT, T, gate, sgp);
  gemmD_kernel<<<256, 512, 0, stream>>>(T, WdT, P);
  reduce8_kernel<<<2048, 256, 0, stream>>>(P, out, 524288);
}